// Round 1
// baseline (614.379 us; speedup 1.0000x reference)
//
#include <hip/hip_runtime.h>
#include <hip/hip_bf16.h>

#define TT 7
#define CCH 128
#define ICH 64
#define NHW 4096

typedef __attribute__((ext_vector_type(8))) short short8;
typedef __attribute__((ext_vector_type(4))) float floatx4;

static __device__ __forceinline__ short f2bf(float f){
  __hip_bfloat16 h = __float2bfloat16(f);
  return *reinterpret_cast<short*>(&h);
}

// ---------------- weight table: wtab[dy+63][dx+63] = exp(-0.5*(dx^2+dy^2)/std^2)
__global__ void k_wtab(float* __restrict__ wtab, const float* __restrict__ stdp){
  int i = blockIdx.x*256 + threadIdx.x;
  if (i >= 127*127) return;
  int dy = i / 127 - 63;
  int dx = i % 127 - 63;
  float s = stdp[0];
  wtab[i] = __expf(-0.5f*(float)(dx*dx + dy*dy)/(s*s));
}

// ---------------- groupnorm stats: 7 frames x 32 groups, 4*4096 elems each
__global__ void k_stats(const float* __restrict__ x, float* __restrict__ mu,
                        float* __restrict__ rstd, float* __restrict__ qacc){
  int t = blockIdx.x >> 5, g = blockIdx.x & 31;
  const float* base = x + ((size_t)t*CCH + g*4) * NHW;
  float s = 0.f, s2 = 0.f;
  for (int i = threadIdx.x; i < 4*NHW; i += 256){
    float v = base[i]; s += v; s2 += v*v;
  }
  #pragma unroll
  for (int off = 32; off; off >>= 1){
    s  += __shfl_down(s, off);
    s2 += __shfl_down(s2, off);
  }
  __shared__ float sh[8];
  int w = threadIdx.x >> 6;
  if ((threadIdx.x & 63) == 0){ sh[w] = s; sh[4+w] = s2; }
  __syncthreads();
  if (threadIdx.x == 0){
    float S  = sh[0]+sh[1]+sh[2]+sh[3];
    float S2 = sh[4]+sh[5]+sh[6]+sh[7];
    float m  = S * (1.f/16384.f);
    float var = S2 * (1.f/16384.f) - m*m;
    mu[blockIdx.x]   = m;
    rstd[blockIdx.x] = rsqrtf(var + 1e-6f);
    if (blockIdx.x == 0) qacc[0] = 0.f;
  }
}

// ---------------- fold GN into conv weights; store transposed [t][c][o]
__global__ void k_fold(const float* __restrict__ gw, const float* __restrict__ gb,
                       const float* __restrict__ thw, const float* __restrict__ thb,
                       const float* __restrict__ phw, const float* __restrict__ phb,
                       const float* __restrict__ gamma, const float* __restrict__ beta,
                       const float* __restrict__ mu, const float* __restrict__ rstd,
                       float* __restrict__ WfT_th, float* __restrict__ bf_th,
                       float* __restrict__ WfT_g,  float* __restrict__ bf_g,
                       float* __restrict__ WfT_phi, float* __restrict__ bf_phi){
  int idx = blockIdx.x*256 + threadIdx.x;
  if (idx >= 960) return;
  const float *W, *B; float *WfT, *bfo; int t, o;
  if (idx < 448){ t = idx >> 6; o = idx & 63; W = thw; B = thb; WfT = WfT_th + (size_t)t*CCH*ICH; bfo = bf_th + t*64; }
  else if (idx < 896){ int j = idx - 448; t = j >> 6; o = j & 63; W = gw; B = gb; WfT = WfT_g + (size_t)t*CCH*ICH; bfo = bf_g + t*64; }
  else { t = 3; o = idx - 896; W = phw; B = phb; WfT = WfT_phi; bfo = bf_phi; }
  float bias = B[o];
  for (int c = 0; c < CCH; ++c){
    int g = c >> 2;
    float rs = rstd[t*32+g], m = mu[t*32+g];
    float a = gamma[c]*rs;
    float w = W[o*CCH + c];
    WfT[c*ICH + o] = w * a;
    bias += w * (beta[c] - m*a);
  }
  bfo[o] = bias;
}

// ---------------- transpose wz_w (128x448)->wzT[448][128], wz1_w (128x64)->wz1T[64][128]
__global__ void k_wzT(const float* __restrict__ wz, const float* __restrict__ wz1,
                      float* __restrict__ wzT, float* __restrict__ wz1T){
  int idx = blockIdx.x*256 + threadIdx.x;
  if (idx < 128*448){ int o = idx / 448, k = idx % 448; wzT[k*128+o] = wz[idx]; }
  if (idx < 128*64) { int o = idx / 64,  c = idx % 64;  wz1T[c*128+o] = wz1[idx]; }
}

// ---------------- conv1x1 (GN folded): theta^T[t][n][c] bf16, g[t][c][n] bf16, phi (t==3)
__global__ __launch_bounds__(256) void k_conv1(const float* __restrict__ x,
    const float* __restrict__ WfT_th, const float* __restrict__ bf_th,
    const float* __restrict__ WfT_g,  const float* __restrict__ bf_g,
    const float* __restrict__ WfT_phi, const float* __restrict__ bf_phi,
    __hip_bfloat16* __restrict__ thetaT, __hip_bfloat16* __restrict__ g_nat,
    __hip_bfloat16* __restrict__ phi_bf, float* __restrict__ phi_f32){
  int t = blockIdx.y;
  int n = blockIdx.x*256 + threadIdx.x;
  const float* xb = x + (size_t)t*CCH*NHW + n;
  float acc[64];

  { // theta
    const float* Wt = WfT_th + (size_t)t*CCH*ICH;
    const float* bb = bf_th + t*64;
    #pragma unroll
    for (int o = 0; o < 64; ++o) acc[o] = bb[o];
    for (int c = 0; c < CCH; ++c){
      float xv = xb[(size_t)c*NHW];
      const float* wc = Wt + c*ICH;
      #pragma unroll
      for (int o = 0; o < 64; ++o) acc[o] += wc[o]*xv;
    }
    short* dst = reinterpret_cast<short*>(thetaT) + ((size_t)t*NHW + n)*ICH;
    #pragma unroll
    for (int o8 = 0; o8 < 8; ++o8){
      short8 pk;
      #pragma unroll
      for (int v = 0; v < 8; ++v) pk[v] = f2bf(acc[o8*8+v]);
      *reinterpret_cast<short8*>(dst + o8*8) = pk;
    }
  }
  { // g
    const float* Wt = WfT_g + (size_t)t*CCH*ICH;
    const float* bb = bf_g + t*64;
    #pragma unroll
    for (int o = 0; o < 64; ++o) acc[o] = bb[o];
    for (int c = 0; c < CCH; ++c){
      float xv = xb[(size_t)c*NHW];
      const float* wc = Wt + c*ICH;
      #pragma unroll
      for (int o = 0; o < 64; ++o) acc[o] += wc[o]*xv;
    }
    #pragma unroll
    for (int o = 0; o < 64; ++o)
      g_nat[((size_t)t*ICH + o)*NHW + n] = __float2bfloat16(acc[o]);
  }
  if (t == 3){ // phi
    #pragma unroll
    for (int o = 0; o < 64; ++o) acc[o] = bf_phi[o];
    for (int c = 0; c < CCH; ++c){
      float xv = xb[(size_t)c*NHW];
      const float* wc = WfT_phi + c*ICH;
      #pragma unroll
      for (int o = 0; o < 64; ++o) acc[o] += wc[o]*xv;
    }
    short* dst = reinterpret_cast<short*>(phi_bf) + (size_t)n*ICH;
    float* df  = phi_f32 + (size_t)n*ICH;
    #pragma unroll
    for (int o8 = 0; o8 < 8; ++o8){
      short8 pk;
      #pragma unroll
      for (int v = 0; v < 8; ++v) pk[v] = f2bf(acc[o8*8+v]);
      *reinterpret_cast<short8*>(dst + o8*8) = pk;
      float4 pf;
      pf.x = acc[o8*8+0]; pf.y = acc[o8*8+1]; pf.z = acc[o8*8+2]; pf.w = acc[o8*8+3];
      *reinterpret_cast<float4*>(df + o8*8) = pf;
      pf.x = acc[o8*8+4]; pf.y = acc[o8*8+5]; pf.z = acc[o8*8+6]; pf.w = acc[o8*8+7];
      *reinterpret_cast<float4*>(df + o8*8 + 4) = pf;
    }
  }
}

// ---------------- flash attention per frame: corr[t*64+c][n] = (softmax(phi theta^T) .* W) g^T
__global__ __launch_bounds__(256) void k_attn(
    const __hip_bfloat16* __restrict__ phi_bf,   // [n][64]
    const __hip_bfloat16* __restrict__ thetaT,   // [t][m][64]
    const __hip_bfloat16* __restrict__ g_nat,    // [t][c][m]
    const float* __restrict__ wtab,              // [127][127]
    float* __restrict__ corr)                    // [448][4096]
{
  const int t    = blockIdx.y;
  const int w    = threadIdx.x >> 6;
  const int lane = threadIdx.x & 63;
  const int l15  = lane & 15;
  const int quad = lane >> 4;
  const int row0 = blockIdx.x*64 + w*16;

  __shared__ short Plds[4][16][72];   // padded: ds_read_b128 -> 2-way (free)

  const short* phi_s = reinterpret_cast<const short*>(phi_bf);
  const short* th_s  = reinterpret_cast<const short*>(thetaT) + (size_t)t*NHW*ICH;
  const short* g_s   = reinterpret_cast<const short*>(g_nat)  + (size_t)t*ICH*NHW;

  short8 aq0 = *reinterpret_cast<const short8*>(phi_s + (size_t)(row0 + l15)*ICH + quad*8);
  short8 aq1 = *reinterpret_cast<const short8*>(phi_s + (size_t)(row0 + l15)*ICH + 32 + quad*8);

  float mrun[4], Zrun[4];
  floatx4 oacc[4];
  int rowbase[4], nrow[4];
  #pragma unroll
  for (int r = 0; r < 4; ++r){
    mrun[r] = -1e30f; Zrun[r] = 0.f;
    oacc[r] = (floatx4){0.f,0.f,0.f,0.f};
    nrow[r] = row0 + quad*4 + r;
    rowbase[r] = (nrow[r] >> 6)*127 + (nrow[r] & 63) + 63*127 + 63;
  }

  for (int m0 = 0; m0 < NHW; m0 += 64){
    // ---- S = phi @ theta^T (16 rows x 64 cols per wave)
    floatx4 s[4];
    #pragma unroll
    for (int mc = 0; mc < 4; ++mc){
      const short* bp = th_s + (size_t)(m0 + mc*16 + l15)*ICH + quad*8;
      short8 b0 = *reinterpret_cast<const short8*>(bp);
      short8 b1 = *reinterpret_cast<const short8*>(bp + 32);
      floatx4 acc = (floatx4){0.f,0.f,0.f,0.f};
      acc = __builtin_amdgcn_mfma_f32_16x16x32_bf16(aq0, b0, acc, 0, 0, 0);
      acc = __builtin_amdgcn_mfma_f32_16x16x32_bf16(aq1, b1, acc, 0, 0, 0);
      s[mc] = acc;
    }
    // ---- online softmax
    float mnew[4], alpha[4], psum[4];
    #pragma unroll
    for (int r = 0; r < 4; ++r){
      float tm = fmaxf(fmaxf(s[0][r], s[1][r]), fmaxf(s[2][r], s[3][r]));
      #pragma unroll
      for (int off = 8; off; off >>= 1) tm = fmaxf(tm, __shfl_xor(tm, off));
      mnew[r]  = fmaxf(mrun[r], tm);
      alpha[r] = __expf(mrun[r] - mnew[r]);
      mrun[r]  = mnew[r];
      psum[r]  = 0.f;
    }
    #pragma unroll
    for (int mc = 0; mc < 4; ++mc){
      int m = m0 + mc*16 + l15;
      int mterm = (m >> 6)*127 + (m & 63);
      #pragma unroll
      for (int r = 0; r < 4; ++r){
        float p = __expf(s[mc][r] - mnew[r]);
        psum[r] += p;
        float wgt = wtab[rowbase[r] - mterm];
        Plds[w][quad*4+r][mc*16+l15] = f2bf(p * wgt);
      }
    }
    #pragma unroll
    for (int r = 0; r < 4; ++r){
      float ps = psum[r];
      #pragma unroll
      for (int off = 8; off; off >>= 1) ps += __shfl_xor(ps, off);
      Zrun[r] = Zrun[r]*alpha[r] + ps;
    }
    #pragma unroll
    for (int cc = 0; cc < 4; ++cc)
      #pragma unroll
      for (int r = 0; r < 4; ++r) oacc[cc][r] *= alpha[r];
    // ---- O += (P .* W) @ V   (V[m][c] = g[t][c][m])
    short8 ap0 = *reinterpret_cast<const short8*>(&Plds[w][l15][quad*8]);
    short8 ap1 = *reinterpret_cast<const short8*>(&Plds[w][l15][32 + quad*8]);
    #pragma unroll
    for (int cc = 0; cc < 4; ++cc){
      const short* vp = g_s + (size_t)(cc*16 + l15)*NHW + m0 + quad*8;
      short8 v0 = *reinterpret_cast<const short8*>(vp);
      short8 v1 = *reinterpret_cast<const short8*>(vp + 32);
      oacc[cc] = __builtin_amdgcn_mfma_f32_16x16x32_bf16(ap0, v0, oacc[cc], 0, 0, 0);
      oacc[cc] = __builtin_amdgcn_mfma_f32_16x16x32_bf16(ap1, v1, oacc[cc], 0, 0, 0);
    }
  }
  // ---- epilogue: corr[(t*64+c)][n] = O / Z
  #pragma unroll
  for (int cc = 0; cc < 4; ++cc){
    int c = cc*16 + l15;
    float* dst = corr + ((size_t)t*ICH + c)*NHW;
    #pragma unroll
    for (int r = 0; r < 4; ++r)
      dst[nrow[r]] = oacc[cc][r] / Zrun[r];
  }
}

// ---------------- memory-bank path: f1 softmax, y1 (stored [c][n]), qloss
__global__ __launch_bounds__(256) void k_mb(const float* __restrict__ phi32,
    const float* __restrict__ mb, float* __restrict__ y1T, float* __restrict__ qacc){
  __shared__ __hip_bfloat16 mbT[256][66];
  __shared__ float shp[4][256];
  __shared__ float shphi[4][64];
  for (int idx = threadIdx.x; idx < 64*256; idx += 256){
    int c = idx >> 8, k = idx & 255;
    mbT[k][c] = __float2bfloat16(mb[idx]);
  }
  int w = threadIdx.x >> 6, lane = threadIdx.x & 63;
  int n = blockIdx.x*4 + w;
  shphi[w][lane] = phi32[(size_t)n*64 + lane];
  __syncthreads();

  float f[4] = {0.f,0.f,0.f,0.f};
  for (int c = 0; c < 64; ++c){
    float pv = shphi[w][c];
    const float* mrow = mb + (size_t)c*256;
    #pragma unroll
    for (int j = 0; j < 4; ++j) f[j] += pv * mrow[lane + 64*j];
  }
  float mx = -1e30f;
  #pragma unroll
  for (int j = 0; j < 4; ++j){ f[j] *= 0.125f; mx = fmaxf(mx, f[j]); }
  #pragma unroll
  for (int off = 32; off; off >>= 1) mx = fmaxf(mx, __shfl_xor(mx, off));
  float Z = 0.f;
  #pragma unroll
  for (int j = 0; j < 4; ++j){
    float p = __expf(f[j] - mx);
    Z += p;
    shp[w][lane + 64*j] = p;
  }
  #pragma unroll
  for (int off = 32; off; off >>= 1) Z += __shfl_xor(Z, off);
  float inv = 1.f / Z;

  float acc = 0.f;
  for (int k = 0; k < 256; ++k)
    acc += shp[w][k] * __bfloat162float(mbT[k][lane]);
  float yv = acc * inv;
  y1T[(size_t)lane*NHW + n] = yv;

  float d = fabsf(shphi[w][lane] - yv);
  #pragma unroll
  for (int off = 32; off; off >>= 1) d += __shfl_xor(d, off);
  if (lane == 0) atomicAdd(qacc, d);
}

// ---------------- z = wz@corr + wz_b + q + wz1@y1 + wz1_b; plus qloss
__global__ __launch_bounds__(256) void k_z(const float* __restrict__ corr,
    const float* __restrict__ y1T, const float* __restrict__ x,
    const float* __restrict__ wzT, const float* __restrict__ wz_b,
    const float* __restrict__ wz1T, const float* __restrict__ wz1_b,
    const float* __restrict__ qacc, float* __restrict__ out){
  int n  = blockIdx.x*256 + threadIdx.x;
  int o0 = blockIdx.y*8;
  float acc[8];
  #pragma unroll
  for (int i = 0; i < 8; ++i) acc[i] = wz_b[o0+i] + wz1_b[o0+i];
  for (int k = 0; k < 448; ++k){
    float v = corr[(size_t)k*NHW + n];
    const float* wp = wzT + k*128 + o0;
    #pragma unroll
    for (int i = 0; i < 8; ++i) acc[i] += wp[i]*v;
  }
  for (int c = 0; c < 64; ++c){
    float v = y1T[(size_t)c*NHW + n];
    const float* wp = wz1T + c*128 + o0;
    #pragma unroll
    for (int i = 0; i < 8; ++i) acc[i] += wp[i]*v;
  }
  #pragma unroll
  for (int i = 0; i < 8; ++i)
    out[(size_t)(o0+i)*NHW + n] = acc[i] + x[((size_t)3*CCH + o0+i)*NHW + n];
  if (blockIdx.x == 0 && blockIdx.y == 0 && threadIdx.x == 0)
    out[(size_t)CCH*NHW] = qacc[0] * (1.f/262144.f);
}

extern "C" void kernel_launch(void* const* d_in, const int* in_sizes, int n_in,
                              void* d_out, int out_size, void* d_ws, size_t ws_size,
                              hipStream_t stream){
  const float* x     = (const float*)d_in[0];
  const float* gamma = (const float*)d_in[1];
  const float* beta  = (const float*)d_in[2];
  const float* g_w   = (const float*)d_in[3];
  const float* g_b   = (const float*)d_in[4];
  const float* th_w  = (const float*)d_in[5];
  const float* th_b  = (const float*)d_in[6];
  const float* ph_w  = (const float*)d_in[7];
  const float* ph_b  = (const float*)d_in[8];
  const float* wz_w  = (const float*)d_in[9];
  const float* wz_b  = (const float*)d_in[10];
  const float* wz1_w = (const float*)d_in[11];
  const float* wz1_b = (const float*)d_in[12];
  const float* mb    = (const float*)d_in[13];
  const float* stdp  = (const float*)d_in[14];
  float* out = (float*)d_out;

  char* ws = (char*)d_ws;
  size_t off = 0;
  auto alloc = [&](size_t bytes)->char*{
    char* p = ws + off; off += (bytes + 255) & ~(size_t)255; return p;
  };
  float* wtab    = (float*)alloc(127*127*4);
  float* mu      = (float*)alloc(224*4);
  float* rstd    = (float*)alloc(224*4);
  float* qacc    = (float*)alloc(4);
  float* WfT_th  = (float*)alloc((size_t)TT*CCH*ICH*4);
  float* bf_th   = (float*)alloc(TT*64*4);
  float* WfT_g   = (float*)alloc((size_t)TT*CCH*ICH*4);
  float* bf_g    = (float*)alloc(TT*64*4);
  float* WfT_phi = (float*)alloc(CCH*ICH*4);
  float* bf_phi  = (float*)alloc(64*4);
  float* wzT     = (float*)alloc(448*128*4);
  float* wz1T    = (float*)alloc(64*128*4);
  __hip_bfloat16* thetaT = (__hip_bfloat16*)alloc((size_t)TT*NHW*ICH*2);
  __hip_bfloat16* g_nat  = (__hip_bfloat16*)alloc((size_t)TT*NHW*ICH*2);
  __hip_bfloat16* phi_bf = (__hip_bfloat16*)alloc((size_t)NHW*ICH*2);
  float* phi_f32 = (float*)alloc((size_t)NHW*ICH*4);
  float* corr    = (float*)alloc((size_t)TT*ICH*NHW*4);
  float* y1T     = (float*)alloc((size_t)ICH*NHW*4);

  k_wtab <<<64, 256, 0, stream>>>(wtab, stdp);
  k_stats<<<224, 256, 0, stream>>>(x, mu, rstd, qacc);
  k_fold <<<4, 256, 0, stream>>>(g_w, g_b, th_w, th_b, ph_w, ph_b, gamma, beta,
                                 mu, rstd, WfT_th, bf_th, WfT_g, bf_g, WfT_phi, bf_phi);
  k_wzT  <<<224, 256, 0, stream>>>(wz_w, wz1_w, wzT, wz1T);
  k_conv1<<<dim3(16,7), 256, 0, stream>>>(x, WfT_th, bf_th, WfT_g, bf_g, WfT_phi, bf_phi,
                                          thetaT, g_nat, phi_bf, phi_f32);
  k_attn <<<dim3(64,7), 256, 0, stream>>>(phi_bf, thetaT, g_nat, wtab, corr);
  k_mb   <<<1024, 256, 0, stream>>>(phi_f32, mb, y1T, qacc);
  k_z    <<<dim3(16,16), 256, 0, stream>>>(corr, y1T, x, wzT, wz_b, wz1T, wz1_b, qacc, out);
}

// Round 2
// 487.683 us; speedup vs baseline: 1.2598x; 1.2598x over previous
//
#include <hip/hip_runtime.h>
#include <hip/hip_bf16.h>

#define TT 7
#define CCH 128
#define ICH 64
#define NHW 4096
#define NSPLIT 4
#define MCHUNK (NHW/NSPLIT)

typedef __attribute__((ext_vector_type(8))) short short8;
typedef __attribute__((ext_vector_type(4))) short sshort4;
typedef __attribute__((ext_vector_type(4))) float floatx4;

static __device__ __forceinline__ short f2bf(float f){
  __hip_bfloat16 h = __float2bfloat16(f);
  return *reinterpret_cast<short*>(&h);
}

// ---------------- separable weight table: wd[d] = exp(-0.5*d^2/std^2), d in [0,64)
__global__ void k_wd(float* __restrict__ wd, const float* __restrict__ stdp){
  int d = threadIdx.x;
  if (d < 64){
    float s = stdp[0];
    wd[d] = __expf(-0.5f*(float)(d*d)/(s*s));
  }
}

// ---------------- groupnorm stats: 7 frames x 32 groups, 4*4096 elems each
__global__ void k_stats(const float* __restrict__ x, float* __restrict__ mu,
                        float* __restrict__ rstd, float* __restrict__ qacc){
  int t = blockIdx.x >> 5, g = blockIdx.x & 31;
  const float* base = x + ((size_t)t*CCH + g*4) * NHW;
  float s = 0.f, s2 = 0.f;
  for (int i = threadIdx.x; i < 4*NHW; i += 256){
    float v = base[i]; s += v; s2 += v*v;
  }
  #pragma unroll
  for (int off = 32; off; off >>= 1){
    s  += __shfl_down(s, off);
    s2 += __shfl_down(s2, off);
  }
  __shared__ float sh[8];
  int w = threadIdx.x >> 6;
  if ((threadIdx.x & 63) == 0){ sh[w] = s; sh[4+w] = s2; }
  __syncthreads();
  if (threadIdx.x == 0){
    float S  = sh[0]+sh[1]+sh[2]+sh[3];
    float S2 = sh[4]+sh[5]+sh[6]+sh[7];
    float m  = S * (1.f/16384.f);
    float var = S2 * (1.f/16384.f) - m*m;
    mu[blockIdx.x]   = m;
    rstd[blockIdx.x] = rsqrtf(var + 1e-6f);
    if (blockIdx.x == 0) qacc[0] = 0.f;
  }
}

// ---------------- fold GN into conv weights; store transposed [t][c][o]
__global__ void k_fold(const float* __restrict__ gw, const float* __restrict__ gb,
                       const float* __restrict__ thw, const float* __restrict__ thb,
                       const float* __restrict__ phw, const float* __restrict__ phb,
                       const float* __restrict__ gamma, const float* __restrict__ beta,
                       const float* __restrict__ mu, const float* __restrict__ rstd,
                       float* __restrict__ WfT_th, float* __restrict__ bf_th,
                       float* __restrict__ WfT_g,  float* __restrict__ bf_g,
                       float* __restrict__ WfT_phi, float* __restrict__ bf_phi){
  int idx = blockIdx.x*256 + threadIdx.x;
  if (idx >= 960) return;
  const float *W, *B; float *WfT, *bfo; int t, o;
  if (idx < 448){ t = idx >> 6; o = idx & 63; W = thw; B = thb; WfT = WfT_th + (size_t)t*CCH*ICH; bfo = bf_th + t*64; }
  else if (idx < 896){ int j = idx - 448; t = j >> 6; o = j & 63; W = gw; B = gb; WfT = WfT_g + (size_t)t*CCH*ICH; bfo = bf_g + t*64; }
  else { t = 3; o = idx - 896; W = phw; B = phb; WfT = WfT_phi; bfo = bf_phi; }
  float bias = B[o];
  for (int c = 0; c < CCH; ++c){
    int g = c >> 2;
    float rs = rstd[t*32+g], m = mu[t*32+g];
    float a = gamma[c]*rs;
    float w = W[o*CCH + c];
    WfT[c*ICH + o] = w * a;
    bias += w * (beta[c] - m*a);
  }
  bfo[o] = bias;
}

// ---------------- transpose wz_w (128x448)->wzT[448][128], wz1_w (128x64)->wz1T[64][128]
__global__ void k_wzT(const float* __restrict__ wz, const float* __restrict__ wz1,
                      float* __restrict__ wzT, float* __restrict__ wz1T){
  int idx = blockIdx.x*256 + threadIdx.x;
  if (idx < 128*448){ int o = idx / 448, k = idx % 448; wzT[k*128+o] = wz[idx]; }
  if (idx < 128*64) { int o = idx / 64,  c = idx % 64;  wz1T[c*128+o] = wz1[idx]; }
}

// ---------------- conv1x1 (GN folded), split over (t, out-half, {theta/phi | g})
__global__ __launch_bounds__(256) void k_conv(const float* __restrict__ x,
    const float* __restrict__ WfT_th, const float* __restrict__ bf_th,
    const float* __restrict__ WfT_g,  const float* __restrict__ bf_g,
    const float* __restrict__ WfT_phi, const float* __restrict__ bf_phi,
    __hip_bfloat16* __restrict__ thetaT, __hip_bfloat16* __restrict__ g_nat,
    __hip_bfloat16* __restrict__ phi_bf, float* __restrict__ phi_f32){
  int t = blockIdx.y >> 1, half = blockIdx.y & 1;
  int n = blockIdx.x*256 + threadIdx.x;
  const float* xb = x + (size_t)t*CCH*NHW + n;
  float acc[32];

  if (blockIdx.z == 0){
    { // theta half
      const float* Wt = WfT_th + (size_t)t*CCH*ICH + half*32;
      const float* bb = bf_th + t*64 + half*32;
      #pragma unroll
      for (int o = 0; o < 32; ++o) acc[o] = bb[o];
      for (int c = 0; c < CCH; ++c){
        float xv = xb[(size_t)c*NHW];
        const float* wc = Wt + c*ICH;
        #pragma unroll
        for (int o = 0; o < 32; ++o) acc[o] += wc[o]*xv;
      }
      short* dst = reinterpret_cast<short*>(thetaT) + ((size_t)t*NHW + n)*ICH + half*32;
      #pragma unroll
      for (int o8 = 0; o8 < 4; ++o8){
        short8 pk;
        #pragma unroll
        for (int v = 0; v < 8; ++v) pk[v] = f2bf(acc[o8*8+v]);
        *reinterpret_cast<short8*>(dst + o8*8) = pk;
      }
    }
    if (t == 3){ // phi half
      const float* Wt = WfT_phi + half*32;
      #pragma unroll
      for (int o = 0; o < 32; ++o) acc[o] = bf_phi[half*32 + o];
      for (int c = 0; c < CCH; ++c){
        float xv = xb[(size_t)c*NHW];
        const float* wc = Wt + c*ICH;
        #pragma unroll
        for (int o = 0; o < 32; ++o) acc[o] += wc[o]*xv;
      }
      short* dst = reinterpret_cast<short*>(phi_bf) + (size_t)n*ICH + half*32;
      float* df  = phi_f32 + (size_t)n*ICH + half*32;
      #pragma unroll
      for (int o8 = 0; o8 < 4; ++o8){
        short8 pk;
        #pragma unroll
        for (int v = 0; v < 8; ++v) pk[v] = f2bf(acc[o8*8+v]);
        *reinterpret_cast<short8*>(dst + o8*8) = pk;
        float4 pf;
        pf.x = acc[o8*8+0]; pf.y = acc[o8*8+1]; pf.z = acc[o8*8+2]; pf.w = acc[o8*8+3];
        *reinterpret_cast<float4*>(df + o8*8) = pf;
        pf.x = acc[o8*8+4]; pf.y = acc[o8*8+5]; pf.z = acc[o8*8+6]; pf.w = acc[o8*8+7];
        *reinterpret_cast<float4*>(df + o8*8 + 4) = pf;
      }
    }
  } else { // g half
    const float* Wt = WfT_g + (size_t)t*CCH*ICH + half*32;
    const float* bb = bf_g + t*64 + half*32;
    #pragma unroll
    for (int o = 0; o < 32; ++o) acc[o] = bb[o];
    for (int c = 0; c < CCH; ++c){
      float xv = xb[(size_t)c*NHW];
      const float* wc = Wt + c*ICH;
      #pragma unroll
      for (int o = 0; o < 32; ++o) acc[o] += wc[o]*xv;
    }
    #pragma unroll
    for (int o = 0; o < 32; ++o)
      g_nat[((size_t)t*ICH + half*32 + o)*NHW + n] = __float2bfloat16(acc[o]);
  }
}

// ---------------- split-K flash attention (fixed-shift softmax, separable weight)
// Opart[(t*NSPLIT+sp)*64 + c][n] = sum_{m in chunk} exp(s-8)*wgt * g[c][m]
// Zpart[(t*NSPLIT+sp)][n]        = sum_{m in chunk} exp(s-8)
__global__ __launch_bounds__(256, 5) void k_attn(
    const __hip_bfloat16* __restrict__ phi_bf,   // [n][64]
    const __hip_bfloat16* __restrict__ thetaT,   // [t][m][64]
    const __hip_bfloat16* __restrict__ g_nat,    // [t][c][m]
    const float* __restrict__ wd,                // [64]
    float* __restrict__ Opart, float* __restrict__ Zpart)
{
  const int t    = blockIdx.z;
  const int sp   = blockIdx.y;
  const int w    = threadIdx.x >> 6;
  const int lane = threadIdx.x & 63;
  const int l15  = lane & 15;
  const int quad = lane >> 4;
  const int row0 = blockIdx.x*64 + w*16;   // base n of this wave
  const int yn   = blockIdx.x;             // y coord of all n in block

  __shared__ short Plds[4][16][72];        // [wave][n-local][m + pad]
  __shared__ float wdsh[64];
  if (threadIdx.x < 64) wdsh[threadIdx.x] = wd[threadIdx.x];
  __syncthreads();

  const short* phi_s = reinterpret_cast<const short*>(phi_bf);
  const short* th_s  = reinterpret_cast<const short*>(thetaT) + (size_t)t*NHW*ICH;
  const short* g_s   = reinterpret_cast<const short*>(g_nat)  + (size_t)t*ICH*NHW;

  // B-frag: phi rows (fixed n per lane)
  short8 bq0 = *reinterpret_cast<const short8*>(phi_s + (size_t)(row0 + l15)*ICH + quad*8);
  short8 bq1 = *reinterpret_cast<const short8*>(phi_s + (size_t)(row0 + l15)*ICH + 32 + quad*8);

  // loop-invariant x-direction weight factors
  float wxv[16];
  const int xn = w*16 + l15;
  #pragma unroll
  for (int mc = 0; mc < 4; ++mc)
    #pragma unroll
    for (int r = 0; r < 4; ++r){
      int xm = mc*16 + quad*4 + r;
      wxv[mc*4+r] = wdsh[abs(xn - xm)];
    }

  floatx4 oacc[4];
  #pragma unroll
  for (int cc = 0; cc < 4; ++cc) oacc[cc] = (floatx4){0.f,0.f,0.f,0.f};
  float psum = 0.f;

  const int m0beg = sp*MCHUNK;
  const short* thp0 = th_s + (size_t)(m0beg +  0 + l15)*ICH + quad*8;
  const short* thp1 = th_s + (size_t)(m0beg + 16 + l15)*ICH + quad*8;
  const short* thp2 = th_s + (size_t)(m0beg + 32 + l15)*ICH + quad*8;
  const short* thp3 = th_s + (size_t)(m0beg + 48 + l15)*ICH + quad*8;
  const short* gp0 = g_s + (size_t)( 0 + l15)*NHW + m0beg + quad*8;
  const short* gp1 = g_s + (size_t)(16 + l15)*NHW + m0beg + quad*8;
  const short* gp2 = g_s + (size_t)(32 + l15)*NHW + m0beg + quad*8;
  const short* gp3 = g_s + (size_t)(48 + l15)*NHW + m0beg + quad*8;

  for (int it = 0; it < MCHUNK/64; ++it){
    const int ym = (m0beg >> 6) + it;
    const float wyv = wdsh[abs(yn - ym)];

    // ---- S^T = theta @ phi^T : lane holds fixed n=row0+l15, 16 m values
    floatx4 s[4];
    {
      short8 a0 = *reinterpret_cast<const short8*>(thp0);
      short8 a1 = *reinterpret_cast<const short8*>(thp0 + 32);
      floatx4 acc = (floatx4){0.f,0.f,0.f,0.f};
      acc = __builtin_amdgcn_mfma_f32_16x16x32_bf16(a0, bq0, acc, 0, 0, 0);
      s[0] = __builtin_amdgcn_mfma_f32_16x16x32_bf16(a1, bq1, acc, 0, 0, 0);
    }
    {
      short8 a0 = *reinterpret_cast<const short8*>(thp1);
      short8 a1 = *reinterpret_cast<const short8*>(thp1 + 32);
      floatx4 acc = (floatx4){0.f,0.f,0.f,0.f};
      acc = __builtin_amdgcn_mfma_f32_16x16x32_bf16(a0, bq0, acc, 0, 0, 0);
      s[1] = __builtin_amdgcn_mfma_f32_16x16x32_bf16(a1, bq1, acc, 0, 0, 0);
    }
    {
      short8 a0 = *reinterpret_cast<const short8*>(thp2);
      short8 a1 = *reinterpret_cast<const short8*>(thp2 + 32);
      floatx4 acc = (floatx4){0.f,0.f,0.f,0.f};
      acc = __builtin_amdgcn_mfma_f32_16x16x32_bf16(a0, bq0, acc, 0, 0, 0);
      s[2] = __builtin_amdgcn_mfma_f32_16x16x32_bf16(a1, bq1, acc, 0, 0, 0);
    }
    {
      short8 a0 = *reinterpret_cast<const short8*>(thp3);
      short8 a1 = *reinterpret_cast<const short8*>(thp3 + 32);
      floatx4 acc = (floatx4){0.f,0.f,0.f,0.f};
      acc = __builtin_amdgcn_mfma_f32_16x16x32_bf16(a0, bq0, acc, 0, 0, 0);
      s[3] = __builtin_amdgcn_mfma_f32_16x16x32_bf16(a1, bq1, acc, 0, 0, 0);
    }
    thp0 += 64*ICH; thp1 += 64*ICH; thp2 += 64*ICH; thp3 += 64*ICH;

    // ---- exp + weight + store P^T slab (contiguous in m per lane -> b64)
    #pragma unroll
    for (int mc = 0; mc < 4; ++mc){
      sshort4 pk;
      #pragma unroll
      for (int r = 0; r < 4; ++r){
        float p = __expf(s[mc][r] - 8.f);
        psum += p;
        pk[r] = f2bf(p * wyv * wxv[mc*4+r]);
      }
      *reinterpret_cast<sshort4*>(&Plds[w][l15][mc*16 + quad*4]) = pk;
    }

    // ---- A-frag of P (wave-private LDS; compiler inserts lgkmcnt waits)
    short8 ap0 = *reinterpret_cast<const short8*>(&Plds[w][l15][quad*8]);
    short8 ap1 = *reinterpret_cast<const short8*>(&Plds[w][l15][32 + quad*8]);

    // ---- O += P @ V
    {
      short8 v0 = *reinterpret_cast<const short8*>(gp0);
      short8 v1 = *reinterpret_cast<const short8*>(gp0 + 32);
      oacc[0] = __builtin_amdgcn_mfma_f32_16x16x32_bf16(ap0, v0, oacc[0], 0, 0, 0);
      oacc[0] = __builtin_amdgcn_mfma_f32_16x16x32_bf16(ap1, v1, oacc[0], 0, 0, 0);
    }
    {
      short8 v0 = *reinterpret_cast<const short8*>(gp1);
      short8 v1 = *reinterpret_cast<const short8*>(gp1 + 32);
      oacc[1] = __builtin_amdgcn_mfma_f32_16x16x32_bf16(ap0, v0, oacc[1], 0, 0, 0);
      oacc[1] = __builtin_amdgcn_mfma_f32_16x16x32_bf16(ap1, v1, oacc[1], 0, 0, 0);
    }
    {
      short8 v0 = *reinterpret_cast<const short8*>(gp2);
      short8 v1 = *reinterpret_cast<const short8*>(gp2 + 32);
      oacc[2] = __builtin_amdgcn_mfma_f32_16x16x32_bf16(ap0, v0, oacc[2], 0, 0, 0);
      oacc[2] = __builtin_amdgcn_mfma_f32_16x16x32_bf16(ap1, v1, oacc[2], 0, 0, 0);
    }
    {
      short8 v0 = *reinterpret_cast<const short8*>(gp3);
      short8 v1 = *reinterpret_cast<const short8*>(gp3 + 32);
      oacc[3] = __builtin_amdgcn_mfma_f32_16x16x32_bf16(ap0, v0, oacc[3], 0, 0, 0);
      oacc[3] = __builtin_amdgcn_mfma_f32_16x16x32_bf16(ap1, v1, oacc[3], 0, 0, 0);
    }
    gp0 += 64; gp1 += 64; gp2 += 64; gp3 += 64;
  }

  // ---- epilogue: write partials
  psum += __shfl_xor(psum, 16);
  psum += __shfl_xor(psum, 32);

  float* Ob = Opart + (size_t)(t*NSPLIT + sp)*ICH*NHW;
  #pragma unroll
  for (int cc = 0; cc < 4; ++cc){
    float4 ov;
    ov.x = oacc[cc][0]; ov.y = oacc[cc][1]; ov.z = oacc[cc][2]; ov.w = oacc[cc][3];
    *reinterpret_cast<float4*>(Ob + (size_t)(cc*16 + l15)*NHW + row0 + quad*4) = ov;
  }
  if (quad == 0)
    Zpart[(size_t)(t*NSPLIT + sp)*NHW + row0 + l15] = psum;
}

// ---------------- merge split-K partials: corr[t*64+c][n] = sum_s O / sum_s Z
__global__ __launch_bounds__(256) void k_merge(const float* __restrict__ Opart,
    const float* __restrict__ Zpart, float* __restrict__ corr){
  int n  = blockIdx.x*256 + threadIdx.x;
  int rc = blockIdx.y;            // t*64 + c
  int tt = rc >> 6, c = rc & 63;
  float os = 0.f, zs = 0.f;
  #pragma unroll
  for (int s = 0; s < NSPLIT; ++s){
    os += Opart[((size_t)(tt*NSPLIT + s)*ICH + c)*NHW + n];
    zs += Zpart[(size_t)(tt*NSPLIT + s)*NHW + n];
  }
  corr[(size_t)rc*NHW + n] = os / zs;
}

// ---------------- memory-bank path: f1 softmax, y1 (stored [c][n]), qloss
__global__ __launch_bounds__(256) void k_mb(const float* __restrict__ phi32,
    const float* __restrict__ mb, float* __restrict__ y1T, float* __restrict__ qacc){
  __shared__ __hip_bfloat16 mbT[256][66];
  __shared__ float shp[4][256];
  __shared__ float shphi[4][64];
  for (int idx = threadIdx.x; idx < 64*256; idx += 256){
    int c = idx >> 8, k = idx & 255;
    mbT[k][c] = __float2bfloat16(mb[idx]);
  }
  int w = threadIdx.x >> 6, lane = threadIdx.x & 63;
  int n = blockIdx.x*4 + w;
  shphi[w][lane] = phi32[(size_t)n*64 + lane];
  __syncthreads();

  float f[4] = {0.f,0.f,0.f,0.f};
  for (int c = 0; c < 64; ++c){
    float pv = shphi[w][c];
    const float* mrow = mb + (size_t)c*256;
    #pragma unroll
    for (int j = 0; j < 4; ++j) f[j] += pv * mrow[lane + 64*j];
  }
  float mx = -1e30f;
  #pragma unroll
  for (int j = 0; j < 4; ++j){ f[j] *= 0.125f; mx = fmaxf(mx, f[j]); }
  #pragma unroll
  for (int off = 32; off; off >>= 1) mx = fmaxf(mx, __shfl_xor(mx, off));
  float Z = 0.f;
  #pragma unroll
  for (int j = 0; j < 4; ++j){
    float p = __expf(f[j] - mx);
    Z += p;
    shp[w][lane + 64*j] = p;
  }
  #pragma unroll
  for (int off = 32; off; off >>= 1) Z += __shfl_xor(Z, off);
  float inv = 1.f / Z;

  float acc = 0.f;
  for (int k = 0; k < 256; ++k)
    acc += shp[w][k] * __bfloat162float(mbT[k][lane]);
  float yv = acc * inv;
  y1T[(size_t)lane*NHW + n] = yv;

  float d = fabsf(shphi[w][lane] - yv);
  #pragma unroll
  for (int off = 32; off; off >>= 1) d += __shfl_xor(d, off);
  if (lane == 0) atomicAdd(qacc, d);
}

// ---------------- z = wz@corr + wz_b + q + wz1@y1 + wz1_b; plus qloss
__global__ __launch_bounds__(256) void k_z(const float* __restrict__ corr,
    const float* __restrict__ y1T, const float* __restrict__ x,
    const float* __restrict__ wzT, const float* __restrict__ wz_b,
    const float* __restrict__ wz1T, const float* __restrict__ wz1_b,
    const float* __restrict__ qacc, float* __restrict__ out){
  int n  = blockIdx.x*256 + threadIdx.x;
  int o0 = blockIdx.y*4;
  float acc[4];
  #pragma unroll
  for (int i = 0; i < 4; ++i) acc[i] = wz_b[o0+i] + wz1_b[o0+i];
  for (int k = 0; k < 448; ++k){
    float v = corr[(size_t)k*NHW + n];
    const float* wp = wzT + k*128 + o0;
    #pragma unroll
    for (int i = 0; i < 4; ++i) acc[i] += wp[i]*v;
  }
  for (int c = 0; c < 64; ++c){
    float v = y1T[(size_t)c*NHW + n];
    const float* wp = wz1T + c*128 + o0;
    #pragma unroll
    for (int i = 0; i < 4; ++i) acc[i] += wp[i]*v;
  }
  #pragma unroll
  for (int i = 0; i < 4; ++i)
    out[(size_t)(o0+i)*NHW + n] = acc[i] + x[((size_t)3*CCH + o0+i)*NHW + n];
  if (blockIdx.x == 0 && blockIdx.y == 0 && threadIdx.x == 0)
    out[(size_t)CCH*NHW] = qacc[0] * (1.f/262144.f);
}

extern "C" void kernel_launch(void* const* d_in, const int* in_sizes, int n_in,
                              void* d_out, int out_size, void* d_ws, size_t ws_size,
                              hipStream_t stream){
  const float* x     = (const float*)d_in[0];
  const float* gamma = (const float*)d_in[1];
  const float* beta  = (const float*)d_in[2];
  const float* g_w   = (const float*)d_in[3];
  const float* g_b   = (const float*)d_in[4];
  const float* th_w  = (const float*)d_in[5];
  const float* th_b  = (const float*)d_in[6];
  const float* ph_w  = (const float*)d_in[7];
  const float* ph_b  = (const float*)d_in[8];
  const float* wz_w  = (const float*)d_in[9];
  const float* wz_b  = (const float*)d_in[10];
  const float* wz1_w = (const float*)d_in[11];
  const float* wz1_b = (const float*)d_in[12];
  const float* mb    = (const float*)d_in[13];
  const float* stdp  = (const float*)d_in[14];
  float* out = (float*)d_out;

  char* ws = (char*)d_ws;
  size_t off = 0;
  auto alloc = [&](size_t bytes)->char*{
    char* p = ws + off; off += (bytes + 255) & ~(size_t)255; return p;
  };
  float* wd      = (float*)alloc(64*4);
  float* mu      = (float*)alloc(224*4);
  float* rstd    = (float*)alloc(224*4);
  float* qacc    = (float*)alloc(4);
  float* WfT_th  = (float*)alloc((size_t)TT*CCH*ICH*4);
  float* bf_th   = (float*)alloc(TT*64*4);
  float* WfT_g   = (float*)alloc((size_t)TT*CCH*ICH*4);
  float* bf_g    = (float*)alloc(TT*64*4);
  float* WfT_phi = (float*)alloc(CCH*ICH*4);
  float* bf_phi  = (float*)alloc(64*4);
  float* wzT     = (float*)alloc(448*128*4);
  float* wz1T    = (float*)alloc(64*128*4);
  __hip_bfloat16* thetaT = (__hip_bfloat16*)alloc((size_t)TT*NHW*ICH*2);
  __hip_bfloat16* g_nat  = (__hip_bfloat16*)alloc((size_t)TT*NHW*ICH*2);
  __hip_bfloat16* phi_bf = (__hip_bfloat16*)alloc((size_t)NHW*ICH*2);
  float* phi_f32 = (float*)alloc((size_t)NHW*ICH*4);
  float* corr    = (float*)alloc((size_t)TT*ICH*NHW*4);
  float* y1T     = (float*)alloc((size_t)ICH*NHW*4);
  float* Opart   = (float*)alloc((size_t)TT*NSPLIT*ICH*NHW*4);
  float* Zpart   = (float*)alloc((size_t)TT*NSPLIT*NHW*4);

  k_wd   <<<1, 64, 0, stream>>>(wd, stdp);
  k_stats<<<224, 256, 0, stream>>>(x, mu, rstd, qacc);
  k_fold <<<4, 256, 0, stream>>>(g_w, g_b, th_w, th_b, ph_w, ph_b, gamma, beta,
                                 mu, rstd, WfT_th, bf_th, WfT_g, bf_g, WfT_phi, bf_phi);
  k_wzT  <<<224, 256, 0, stream>>>(wz_w, wz1_w, wzT, wz1T);
  k_conv <<<dim3(16,14,2), 256, 0, stream>>>(x, WfT_th, bf_th, WfT_g, bf_g, WfT_phi, bf_phi,
                                             thetaT, g_nat, phi_bf, phi_f32);
  k_attn <<<dim3(64,NSPLIT,7), 256, 0, stream>>>(phi_bf, thetaT, g_nat, wd, Opart, Zpart);
  k_merge<<<dim3(16,448), 256, 0, stream>>>(Opart, Zpart, corr);
  k_mb   <<<1024, 256, 0, stream>>>(phi_f32, mb, y1T, qacc);
  k_z    <<<dim3(16,32), 256, 0, stream>>>(corr, y1T, x, wzT, wz_b, wz1T, wz1_b, qacc, out);
}

// Round 3
// 365.502 us; speedup vs baseline: 1.6809x; 1.3343x over previous
//
#include <hip/hip_runtime.h>
#include <hip/hip_bf16.h>

#define TT 7
#define CCH 128
#define ICH 64
#define NHW 4096
#define NSPLIT 4
#define MCHUNK (NHW/NSPLIT)

typedef __attribute__((ext_vector_type(8))) short short8;
typedef __attribute__((ext_vector_type(4))) short sshort4;
typedef __attribute__((ext_vector_type(4))) float floatx4;

static __device__ __forceinline__ short f2bf(float f){
  __hip_bfloat16 h = __float2bfloat16(f);
  return *reinterpret_cast<short*>(&h);
}

// ---------------- separable weight table: wd[d] = exp(-0.5*d^2/std^2), d in [0,64)
__global__ void k_wd(float* __restrict__ wd, const float* __restrict__ stdp){
  int d = threadIdx.x;
  if (d < 64){
    float s = stdp[0];
    wd[d] = __expf(-0.5f*(float)(d*d)/(s*s));
  }
}

// ---------------- groupnorm stats: 7 frames x 32 groups, 4*4096 elems each
__global__ void k_stats(const float* __restrict__ x, float* __restrict__ mu,
                        float* __restrict__ rstd, float* __restrict__ qacc){
  int t = blockIdx.x >> 5, g = blockIdx.x & 31;
  const float* base = x + ((size_t)t*CCH + g*4) * NHW;
  float s = 0.f, s2 = 0.f;
  for (int i = threadIdx.x; i < 4*NHW; i += 256){
    float v = base[i]; s += v; s2 += v*v;
  }
  #pragma unroll
  for (int off = 32; off; off >>= 1){
    s  += __shfl_down(s, off);
    s2 += __shfl_down(s2, off);
  }
  __shared__ float sh[8];
  int w = threadIdx.x >> 6;
  if ((threadIdx.x & 63) == 0){ sh[w] = s; sh[4+w] = s2; }
  __syncthreads();
  if (threadIdx.x == 0){
    float S  = sh[0]+sh[1]+sh[2]+sh[3];
    float S2 = sh[4]+sh[5]+sh[6]+sh[7];
    float m  = S * (1.f/16384.f);
    float var = S2 * (1.f/16384.f) - m*m;
    mu[blockIdx.x]   = m;
    rstd[blockIdx.x] = rsqrtf(var + 1e-6f);
    if (blockIdx.x == 0) qacc[0] = 0.f;
  }
}

// ---------------- fold GN into conv weights; store transposed [t][c][o]
__global__ void k_fold(const float* __restrict__ gw, const float* __restrict__ gb,
                       const float* __restrict__ thw, const float* __restrict__ thb,
                       const float* __restrict__ phw, const float* __restrict__ phb,
                       const float* __restrict__ gamma, const float* __restrict__ beta,
                       const float* __restrict__ mu, const float* __restrict__ rstd,
                       float* __restrict__ WfT_th, float* __restrict__ bf_th,
                       float* __restrict__ WfT_g,  float* __restrict__ bf_g,
                       float* __restrict__ WfT_phi, float* __restrict__ bf_phi){
  int idx = blockIdx.x*256 + threadIdx.x;
  if (idx >= 960) return;
  const float *W, *B; float *WfT, *bfo; int t, o;
  if (idx < 448){ t = idx >> 6; o = idx & 63; W = thw; B = thb; WfT = WfT_th + (size_t)t*CCH*ICH; bfo = bf_th + t*64; }
  else if (idx < 896){ int j = idx - 448; t = j >> 6; o = j & 63; W = gw; B = gb; WfT = WfT_g + (size_t)t*CCH*ICH; bfo = bf_g + t*64; }
  else { t = 3; o = idx - 896; W = phw; B = phb; WfT = WfT_phi; bfo = bf_phi; }
  float bias = B[o];
  for (int c = 0; c < CCH; ++c){
    int g = c >> 2;
    float rs = rstd[t*32+g], m = mu[t*32+g];
    float a = gamma[c]*rs;
    float w = W[o*CCH + c];
    WfT[c*ICH + o] = w * a;
    bias += w * (beta[c] - m*a);
  }
  bfo[o] = bias;
}

// ---------------- transpose wz_w (128x448)->wzT[448][128], wz1_w (128x64)->wz1T[64][128]
__global__ void k_wzT(const float* __restrict__ wz, const float* __restrict__ wz1,
                      float* __restrict__ wzT, float* __restrict__ wz1T){
  int idx = blockIdx.x*256 + threadIdx.x;
  if (idx < 128*448){ int o = idx / 448, k = idx % 448; wzT[k*128+o] = wz[idx]; }
  if (idx < 128*64) { int o = idx / 64,  c = idx % 64;  wz1T[c*128+o] = wz1[idx]; }
}

// ---------------- conv1x1 (GN folded), split over (t, out-half, {theta/phi | g})
__global__ __launch_bounds__(256) void k_conv(const float* __restrict__ x,
    const float* __restrict__ WfT_th, const float* __restrict__ bf_th,
    const float* __restrict__ WfT_g,  const float* __restrict__ bf_g,
    const float* __restrict__ WfT_phi, const float* __restrict__ bf_phi,
    __hip_bfloat16* __restrict__ thetaT, __hip_bfloat16* __restrict__ g_nat,
    __hip_bfloat16* __restrict__ phi_bf, float* __restrict__ phi_f32){
  int t = blockIdx.y >> 1, half = blockIdx.y & 1;
  int n = blockIdx.x*256 + threadIdx.x;
  const float* xb = x + (size_t)t*CCH*NHW + n;
  float acc[32];

  if (blockIdx.z == 0){
    { // theta half
      const float* Wt = WfT_th + (size_t)t*CCH*ICH + half*32;
      const float* bb = bf_th + t*64 + half*32;
      #pragma unroll
      for (int o = 0; o < 32; ++o) acc[o] = bb[o];
      for (int c = 0; c < CCH; ++c){
        float xv = xb[(size_t)c*NHW];
        const float* wc = Wt + c*ICH;
        #pragma unroll
        for (int o = 0; o < 32; ++o) acc[o] += wc[o]*xv;
      }
      short* dst = reinterpret_cast<short*>(thetaT) + ((size_t)t*NHW + n)*ICH + half*32;
      #pragma unroll
      for (int o8 = 0; o8 < 4; ++o8){
        short8 pk;
        #pragma unroll
        for (int v = 0; v < 8; ++v) pk[v] = f2bf(acc[o8*8+v]);
        *reinterpret_cast<short8*>(dst + o8*8) = pk;
      }
    }
    if (t == 3){ // phi half
      const float* Wt = WfT_phi + half*32;
      #pragma unroll
      for (int o = 0; o < 32; ++o) acc[o] = bf_phi[half*32 + o];
      for (int c = 0; c < CCH; ++c){
        float xv = xb[(size_t)c*NHW];
        const float* wc = Wt + c*ICH;
        #pragma unroll
        for (int o = 0; o < 32; ++o) acc[o] += wc[o]*xv;
      }
      short* dst = reinterpret_cast<short*>(phi_bf) + (size_t)n*ICH + half*32;
      float* df  = phi_f32 + (size_t)n*ICH + half*32;
      #pragma unroll
      for (int o8 = 0; o8 < 4; ++o8){
        short8 pk;
        #pragma unroll
        for (int v = 0; v < 8; ++v) pk[v] = f2bf(acc[o8*8+v]);
        *reinterpret_cast<short8*>(dst + o8*8) = pk;
        float4 pf;
        pf.x = acc[o8*8+0]; pf.y = acc[o8*8+1]; pf.z = acc[o8*8+2]; pf.w = acc[o8*8+3];
        *reinterpret_cast<float4*>(df + o8*8) = pf;
        pf.x = acc[o8*8+4]; pf.y = acc[o8*8+5]; pf.z = acc[o8*8+6]; pf.w = acc[o8*8+7];
        *reinterpret_cast<float4*>(df + o8*8 + 4) = pf;
      }
    }
  } else { // g half
    const float* Wt = WfT_g + (size_t)t*CCH*ICH + half*32;
    const float* bb = bf_g + t*64 + half*32;
    #pragma unroll
    for (int o = 0; o < 32; ++o) acc[o] = bb[o];
    for (int c = 0; c < CCH; ++c){
      float xv = xb[(size_t)c*NHW];
      const float* wc = Wt + c*ICH;
      #pragma unroll
      for (int o = 0; o < 32; ++o) acc[o] += wc[o]*xv;
    }
    #pragma unroll
    for (int o = 0; o < 32; ++o)
      g_nat[((size_t)t*ICH + half*32 + o)*NHW + n] = __float2bfloat16(acc[o]);
  }
}

// ---------------- split-K flash attention, dedup structure:
// QK: wave w owns m-tile w (16 m x 64 n). PV: wave w owns (c-half w>>1, n-half w&1).
// P crosses waves via double-buffered LDS; one barrier per 64-m block.
__global__ __launch_bounds__(256, 3) void k_attn(
    const __hip_bfloat16* __restrict__ phi_bf,   // [n][64]
    const __hip_bfloat16* __restrict__ thetaT,   // [t][m][64]
    const __hip_bfloat16* __restrict__ g_nat,    // [t][c][m]
    const float* __restrict__ wd,                // [64]
    float* __restrict__ Opart, float* __restrict__ Zpart)
{
  const int t    = blockIdx.z;
  const int sp   = blockIdx.y;
  const int w    = threadIdx.x >> 6;
  const int lane = threadIdx.x & 63;
  const int l15  = lane & 15;
  const int quad = lane >> 4;
  const int n0   = blockIdx.x*64;
  const int yn   = blockIdx.x;

  __shared__ short Plds[2][64][72];   // [buf][n][m + pad]
  __shared__ float wdsh[64];
  __shared__ float Zsh[4][64];
  if (threadIdx.x < 64) wdsh[threadIdx.x] = wd[threadIdx.x];
  __syncthreads();

  const short* phi_s = reinterpret_cast<const short*>(phi_bf);
  const short* th_s  = reinterpret_cast<const short*>(thetaT) + (size_t)t*NHW*ICH;
  const short* g_s   = reinterpret_cast<const short*>(g_nat)  + (size_t)t*ICH*NHW;

  // phi B-frags for ALL 64 n (loop-invariant): [nt][khalf]
  short8 phB[4][2];
  #pragma unroll
  for (int nt = 0; nt < 4; ++nt){
    const short* pp = phi_s + (size_t)(n0 + nt*16 + l15)*ICH + quad*8;
    phB[nt][0] = *reinterpret_cast<const short8*>(pp);
    phB[nt][1] = *reinterpret_cast<const short8*>(pp + 32);
  }

  // x-direction weight factors (loop-invariant): wave's m = w*16+quad*4+r
  float wxv[4][4];
  {
    const int xm = w*16 + quad*4;
    #pragma unroll
    for (int nt = 0; nt < 4; ++nt){
      int xn = nt*16 + l15;
      #pragma unroll
      for (int r = 0; r < 4; ++r) wxv[nt][r] = wdsh[abs(xn - (xm + r))];
    }
  }

  const int ci = w >> 1, nj = w & 1;
  floatx4 oacc[2][2];
  #pragma unroll
  for (int a = 0; a < 2; ++a)
    #pragma unroll
    for (int b = 0; b < 2; ++b) oacc[a][b] = (floatx4){0.f,0.f,0.f,0.f};
  float psum[4] = {0.f,0.f,0.f,0.f};

  int m0 = sp*MCHUNK;
  for (int it = 0; it < MCHUNK/64; ++it, m0 += 64){
    const int buf = it & 1;

    // ---- prefetch g A-frags (consumed after barrier; latency hides under QK)
    short8 gA[2][2];
    #pragma unroll
    for (int ct = 0; ct < 2; ++ct){
      const short* gp = g_s + (size_t)(ci*32 + ct*16 + l15)*NHW + m0 + quad*8;
      gA[ct][0] = *reinterpret_cast<const short8*>(gp);
      gA[ct][1] = *reinterpret_cast<const short8*>(gp + 32);
    }

    // ---- theta A-frag (wave-unique 16 m)
    const short* tp = th_s + (size_t)(m0 + w*16 + l15)*ICH + quad*8;
    short8 a0 = *reinterpret_cast<const short8*>(tp);
    short8 a1 = *reinterpret_cast<const short8*>(tp + 32);

    // ---- S^T[m-tile w][all n] : 8 MFMAs
    floatx4 s[4];
    #pragma unroll
    for (int nt = 0; nt < 4; ++nt){
      floatx4 acc = (floatx4){0.f,0.f,0.f,0.f};
      acc = __builtin_amdgcn_mfma_f32_16x16x32_bf16(a0, phB[nt][0], acc, 0, 0, 0);
      s[nt] = __builtin_amdgcn_mfma_f32_16x16x32_bf16(a1, phB[nt][1], acc, 0, 0, 0);
    }

    // ---- exp + weight + P write (b64, m-contiguous per lane)
    const int ym = m0 >> 6;
    const float wyv = wdsh[abs(yn - ym)];
    #pragma unroll
    for (int nt = 0; nt < 4; ++nt){
      sshort4 pk;
      #pragma unroll
      for (int r = 0; r < 4; ++r){
        float p = __expf(s[nt][r] - 8.f);
        psum[nt] += p;
        pk[r] = f2bf(p * (wyv * wxv[nt][r]));
      }
      *reinterpret_cast<sshort4*>(&Plds[buf][nt*16 + l15][w*16 + quad*4]) = pk;
    }

    __syncthreads();

    // ---- P B-frags (own n-half only: 2x dup instead of 4x)
    short8 pB[2][2];
    #pragma unroll
    for (int nt2 = 0; nt2 < 2; ++nt2){
      const short* pr = &Plds[buf][nj*32 + nt2*16 + l15][quad*8];
      pB[nt2][0] = *reinterpret_cast<const short8*>(pr);
      pB[nt2][1] = *reinterpret_cast<const short8*>(pr + 32);
    }

    // ---- O^T[c-half][n-half] += g @ P : 8 MFMAs
    #pragma unroll
    for (int ct = 0; ct < 2; ++ct)
      #pragma unroll
      for (int nt2 = 0; nt2 < 2; ++nt2){
        oacc[ct][nt2] = __builtin_amdgcn_mfma_f32_16x16x32_bf16(gA[ct][0], pB[nt2][0], oacc[ct][nt2], 0, 0, 0);
        oacc[ct][nt2] = __builtin_amdgcn_mfma_f32_16x16x32_bf16(gA[ct][1], pB[nt2][1], oacc[ct][nt2], 0, 0, 0);
      }
  }

  // ---- epilogue: O partials (col=n=l15 coalesced)
  float* Ob = Opart + (size_t)(t*NSPLIT + sp)*ICH*NHW;
  #pragma unroll
  for (int ct = 0; ct < 2; ++ct)
    #pragma unroll
    for (int nt2 = 0; nt2 < 2; ++nt2){
      int c = ci*32 + ct*16 + quad*4;
      int n = n0 + nj*32 + nt2*16 + l15;
      #pragma unroll
      for (int r = 0; r < 4; ++r)
        Ob[(size_t)(c + r)*NHW + n] = oacc[ct][nt2][r];
    }

  // ---- Z: reduce over quads (shfl), then over waves (LDS)
  #pragma unroll
  for (int nt = 0; nt < 4; ++nt){
    float z = psum[nt];
    z += __shfl_xor(z, 16);
    z += __shfl_xor(z, 32);
    psum[nt] = z;
  }
  if (quad == 0){
    #pragma unroll
    for (int nt = 0; nt < 4; ++nt) Zsh[w][nt*16 + l15] = psum[nt];
  }
  __syncthreads();
  if (threadIdx.x < 64){
    float z = Zsh[0][threadIdx.x] + Zsh[1][threadIdx.x] + Zsh[2][threadIdx.x] + Zsh[3][threadIdx.x];
    Zpart[(size_t)(t*NSPLIT + sp)*NHW + n0 + threadIdx.x] = z;
  }
}

// ---------------- merge split-K partials: corr[t*64+c][n] = sum_s O / sum_s Z
__global__ __launch_bounds__(256) void k_merge(const float* __restrict__ Opart,
    const float* __restrict__ Zpart, float* __restrict__ corr){
  int n  = blockIdx.x*256 + threadIdx.x;
  int rc = blockIdx.y;            // t*64 + c
  int tt = rc >> 6, c = rc & 63;
  float os = 0.f, zs = 0.f;
  #pragma unroll
  for (int s = 0; s < NSPLIT; ++s){
    os += Opart[((size_t)(tt*NSPLIT + s)*ICH + c)*NHW + n];
    zs += Zpart[(size_t)(tt*NSPLIT + s)*NHW + n];
  }
  corr[(size_t)rc*NHW + n] = os / zs;
}

// ---------------- memory-bank path: 16 n per block, mbT staged once
__global__ __launch_bounds__(256) void k_mb(const float* __restrict__ phi32,
    const float* __restrict__ mb, float* __restrict__ y1T, float* __restrict__ qacc){
  __shared__ __hip_bfloat16 mbT[256][66];
  __shared__ float shp[4][256];
  __shared__ float shphi[4][64];
  for (int idx = threadIdx.x; idx < 64*256; idx += 256){
    int c = idx >> 8, k = idx & 255;
    mbT[k][c] = __float2bfloat16(mb[idx]);
  }
  int w = threadIdx.x >> 6, lane = threadIdx.x & 63;
  __syncthreads();

  for (int rep = 0; rep < 4; ++rep){
    int n = blockIdx.x*16 + w*4 + rep;
    shphi[w][lane] = phi32[(size_t)n*64 + lane];

    float f[4] = {0.f,0.f,0.f,0.f};
    for (int c = 0; c < 64; ++c){
      float pv = shphi[w][c];
      const float* mrow = mb + (size_t)c*256;
      #pragma unroll
      for (int j = 0; j < 4; ++j) f[j] += pv * mrow[lane + 64*j];
    }
    float mx = -1e30f;
    #pragma unroll
    for (int j = 0; j < 4; ++j){ f[j] *= 0.125f; mx = fmaxf(mx, f[j]); }
    #pragma unroll
    for (int off = 32; off; off >>= 1) mx = fmaxf(mx, __shfl_xor(mx, off));
    float Z = 0.f;
    #pragma unroll
    for (int j = 0; j < 4; ++j){
      float p = __expf(f[j] - mx);
      Z += p;
      shp[w][lane + 64*j] = p;
    }
    #pragma unroll
    for (int off = 32; off; off >>= 1) Z += __shfl_xor(Z, off);
    float inv = 1.f / Z;

    float acc = 0.f;
    for (int k = 0; k < 256; ++k)
      acc += shp[w][k] * __bfloat162float(mbT[k][lane]);
    float yv = acc * inv;
    y1T[(size_t)lane*NHW + n] = yv;

    float d = fabsf(shphi[w][lane] - yv);
    #pragma unroll
    for (int off = 32; off; off >>= 1) d += __shfl_xor(d, off);
    if (lane == 0) atomicAdd(qacc, d);
  }
}

// ---------------- z: block = 64 n x 32 o; wave-uniform o-range (scalar weights)
__global__ __launch_bounds__(256) void k_z(const float* __restrict__ corr,
    const float* __restrict__ y1T, const float* __restrict__ x,
    const float* __restrict__ wzT, const float* __restrict__ wz_b,
    const float* __restrict__ wz1T, const float* __restrict__ wz1_b,
    const float* __restrict__ qacc, float* __restrict__ out){
  int nl = threadIdx.x & 63;
  int oq = threadIdx.x >> 6;
  int n  = blockIdx.x*64 + nl;
  int ob = __builtin_amdgcn_readfirstlane(blockIdx.y*32 + oq*8);

  float acc[8];
  #pragma unroll
  for (int i = 0; i < 8; ++i) acc[i] = wz_b[ob+i] + wz1_b[ob+i];
  for (int k = 0; k < 448; ++k){
    float v = corr[(size_t)k*NHW + n];
    const float* wp = wzT + k*128 + ob;
    #pragma unroll
    for (int i = 0; i < 8; ++i) acc[i] += wp[i]*v;
  }
  for (int c = 0; c < 64; ++c){
    float v = y1T[(size_t)c*NHW + n];
    const float* wp = wz1T + c*128 + ob;
    #pragma unroll
    for (int i = 0; i < 8; ++i) acc[i] += wp[i]*v;
  }
  #pragma unroll
  for (int i = 0; i < 8; ++i)
    out[(size_t)(ob+i)*NHW + n] = acc[i] + x[((size_t)3*CCH + ob+i)*NHW + n];
  if (blockIdx.x == 0 && blockIdx.y == 0 && threadIdx.x == 0)
    out[(size_t)CCH*NHW] = qacc[0] * (1.f/262144.f);
}

extern "C" void kernel_launch(void* const* d_in, const int* in_sizes, int n_in,
                              void* d_out, int out_size, void* d_ws, size_t ws_size,
                              hipStream_t stream){
  const float* x     = (const float*)d_in[0];
  const float* gamma = (const float*)d_in[1];
  const float* beta  = (const float*)d_in[2];
  const float* g_w   = (const float*)d_in[3];
  const float* g_b   = (const float*)d_in[4];
  const float* th_w  = (const float*)d_in[5];
  const float* th_b  = (const float*)d_in[6];
  const float* ph_w  = (const float*)d_in[7];
  const float* ph_b  = (const float*)d_in[8];
  const float* wz_w  = (const float*)d_in[9];
  const float* wz_b  = (const float*)d_in[10];
  const float* wz1_w = (const float*)d_in[11];
  const float* wz1_b = (const float*)d_in[12];
  const float* mb    = (const float*)d_in[13];
  const float* stdp  = (const float*)d_in[14];
  float* out = (float*)d_out;

  char* ws = (char*)d_ws;
  size_t off = 0;
  auto alloc = [&](size_t bytes)->char*{
    char* p = ws + off; off += (bytes + 255) & ~(size_t)255; return p;
  };
  float* wd      = (float*)alloc(64*4);
  float* mu      = (float*)alloc(224*4);
  float* rstd    = (float*)alloc(224*4);
  float* qacc    = (float*)alloc(4);
  float* WfT_th  = (float*)alloc((size_t)TT*CCH*ICH*4);
  float* bf_th   = (float*)alloc(TT*64*4);
  float* WfT_g   = (float*)alloc((size_t)TT*CCH*ICH*4);
  float* bf_g    = (float*)alloc(TT*64*4);
  float* WfT_phi = (float*)alloc(CCH*ICH*4);
  float* bf_phi  = (float*)alloc(64*4);
  float* wzT     = (float*)alloc(448*128*4);
  float* wz1T    = (float*)alloc(64*128*4);
  __hip_bfloat16* thetaT = (__hip_bfloat16*)alloc((size_t)TT*NHW*ICH*2);
  __hip_bfloat16* g_nat  = (__hip_bfloat16*)alloc((size_t)TT*NHW*ICH*2);
  __hip_bfloat16* phi_bf = (__hip_bfloat16*)alloc((size_t)NHW*ICH*2);
  float* phi_f32 = (float*)alloc((size_t)NHW*ICH*4);
  float* corr    = (float*)alloc((size_t)TT*ICH*NHW*4);
  float* y1T     = (float*)alloc((size_t)ICH*NHW*4);
  float* Opart   = (float*)alloc((size_t)TT*NSPLIT*ICH*NHW*4);
  float* Zpart   = (float*)alloc((size_t)TT*NSPLIT*NHW*4);

  k_wd   <<<1, 64, 0, stream>>>(wd, stdp);
  k_stats<<<224, 256, 0, stream>>>(x, mu, rstd, qacc);
  k_fold <<<4, 256, 0, stream>>>(g_w, g_b, th_w, th_b, ph_w, ph_b, gamma, beta,
                                 mu, rstd, WfT_th, bf_th, WfT_g, bf_g, WfT_phi, bf_phi);
  k_wzT  <<<224, 256, 0, stream>>>(wz_w, wz1_w, wzT, wz1T);
  k_conv <<<dim3(16,14,2), 256, 0, stream>>>(x, WfT_th, bf_th, WfT_g, bf_g, WfT_phi, bf_phi,
                                             thetaT, g_nat, phi_bf, phi_f32);
  k_attn <<<dim3(64,NSPLIT,7), 256, 0, stream>>>(phi_bf, thetaT, g_nat, wd, Opart, Zpart);
  k_merge<<<dim3(16,448), 256, 0, stream>>>(Opart, Zpart, corr);
  k_mb   <<<256, 256, 0, stream>>>(phi_f32, mb, y1T, qacc);
  k_z    <<<dim3(64,4), 256, 0, stream>>>(corr, y1T, x, wzT, wz_b, wz1T, wz1_b, qacc, out);
}